// Round 1
// baseline (13602.557 us; speedup 1.0000x reference)
//
#include <hip/hip_runtime.h>
#include <hip/hip_bf16.h>
#include <math.h>

// Problem constants (from reference)
constexpr int L  = 12;
constexpr int H  = 12;
constexpr int D  = 768;
constexpr int V  = 50257;
constexpr int DH = 64;
constexpr int B  = 4;
constexpr int TV = 64;
constexpr int TT = 448;
constexpr int T  = TV + TT;   // 512
constexpr int M  = B * T;     // 2048 rows in the token dimension

__device__ __forceinline__ float gelu_exact(float v) {
    return 0.5f * v * (1.0f + erff(v * 0.7071067811865476f));
}

// ---------------------------------------------------------------------------
// Embedding: h[b,t,:] = (t<TV ? visual[b,t,:] : wte[x[b,t-TV],:]) + wpe[t,:]
// ---------------------------------------------------------------------------
__global__ __launch_bounds__(256) void embed_kernel(
    const int* __restrict__ x, const float* __restrict__ vis,
    const float* __restrict__ wte, const float* __restrict__ wpe,
    float* __restrict__ h)
{
    const int row = blockIdx.x;          // b*T + t
    const int b = row / T, t = row % T;
    const float* src;
    if (t < TV) src = vis + ((size_t)b * TV + t) * D;
    else        src = wte + (size_t)x[b * TT + (t - TV)] * D;
    const float* pe = wpe + (size_t)t * D;
    float* dst = h + (size_t)row * D;
    for (int i = threadIdx.x; i < D; i += blockDim.x)
        dst[i] = src[i] + pe[i];
}

// ---------------------------------------------------------------------------
// LayerNorm over last dim (D=768). One block (256 thr) per row.
// ---------------------------------------------------------------------------
__global__ __launch_bounds__(256) void ln_kernel(
    const float* __restrict__ in, const float* __restrict__ w,
    const float* __restrict__ bb, float* __restrict__ outp)
{
    const int row = blockIdx.x;
    const float* xr = in + (size_t)row * D;
    float s = 0.f, s2 = 0.f;
    for (int i = threadIdx.x; i < D; i += blockDim.x) {
        float v = xr[i];
        s += v; s2 += v * v;
    }
    // wave reduce (64-wide)
    #pragma unroll
    for (int off = 32; off; off >>= 1) {
        s  += __shfl_down(s,  off);
        s2 += __shfl_down(s2, off);
    }
    __shared__ float ls[4], ls2[4];
    const int wid = threadIdx.x >> 6, lane = threadIdx.x & 63;
    if (lane == 0) { ls[wid] = s; ls2[wid] = s2; }
    __syncthreads();
    if (threadIdx.x == 0) {
        float a = 0.f, c = 0.f;
        for (int i = 0; i < 4; ++i) { a += ls[i]; c += ls2[i]; }
        ls[0] = a; ls2[0] = c;
    }
    __syncthreads();
    const float mean = ls[0] / D;
    const float var  = ls2[0] / D - mean * mean;
    const float inv  = rsqrtf(var + 1e-5f);
    float* orow = outp + (size_t)row * D;
    for (int i = threadIdx.x; i < D; i += blockDim.x)
        orow[i] = (xr[i] - mean) * inv * w[i] + bb[i];
}

// ---------------------------------------------------------------------------
// Generic f32 GEMM: C[M,N] = epilogue(A[M,K] @ B + bias) (+ res)
//   TB=false: B is [K,N] row-major.  TB=true: B is [N,K] row-major (B^T).
//   GELU: apply exact gelu after bias.  RES: add res[M,N] after activation.
// 64x64 tile, BK=16, 256 threads, 4x4 per-thread microtile.
// ---------------------------------------------------------------------------
template<bool TB, bool GELU, bool RES>
__global__ __launch_bounds__(256) void gemm64(
    const float* __restrict__ A, const float* __restrict__ Bm,
    const float* __restrict__ bias, const float* __restrict__ res,
    float* __restrict__ C, int Mm, int N, int K)
{
    __shared__ float As[16][65];
    __shared__ float Bs[16][65];
    const int tid = threadIdx.x;
    const int bm = blockIdx.y * 64;
    const int bn = blockIdx.x * 64;
    const int tx = tid & 15, ty = tid >> 4;

    float acc[4][4] = {};

    const int ar = tid >> 2;          // 0..63
    const int ak = (tid & 3) << 2;    // 0,4,8,12

    for (int k0 = 0; k0 < K; k0 += 16) {
        // A tile -> As[k][m]
        {
            const int m = bm + ar;
            float4 v = make_float4(0.f, 0.f, 0.f, 0.f);
            if (m < Mm)
                v = *reinterpret_cast<const float4*>(&A[(size_t)m * K + k0 + ak]);
            As[ak + 0][ar] = v.x; As[ak + 1][ar] = v.y;
            As[ak + 2][ar] = v.z; As[ak + 3][ar] = v.w;
        }
        if (TB) {
            const int nr = bn + ar;
            float4 v = make_float4(0.f, 0.f, 0.f, 0.f);
            if (nr < N)
                v = *reinterpret_cast<const float4*>(&Bm[(size_t)nr * K + k0 + ak]);
            Bs[ak + 0][ar] = v.x; Bs[ak + 1][ar] = v.y;
            Bs[ak + 2][ar] = v.z; Bs[ak + 3][ar] = v.w;
        } else {
            const int kk = tid >> 4;          // 0..15
            const int nn = (tid & 15) << 2;   // 0..60
            float4 v = make_float4(0.f, 0.f, 0.f, 0.f);
            if (bn + nn < N)
                v = *reinterpret_cast<const float4*>(&Bm[(size_t)(k0 + kk) * N + bn + nn]);
            Bs[kk][nn + 0] = v.x; Bs[kk][nn + 1] = v.y;
            Bs[kk][nn + 2] = v.z; Bs[kk][nn + 3] = v.w;
        }
        __syncthreads();
        #pragma unroll
        for (int kk = 0; kk < 16; ++kk) {
            float a[4], b[4];
            #pragma unroll
            for (int i = 0; i < 4; ++i) a[i] = As[kk][ty * 4 + i];
            #pragma unroll
            for (int j = 0; j < 4; ++j) b[j] = Bs[kk][tx * 4 + j];
            #pragma unroll
            for (int i = 0; i < 4; ++i)
                #pragma unroll
                for (int j = 0; j < 4; ++j)
                    acc[i][j] = fmaf(a[i], b[j], acc[i][j]);
        }
        __syncthreads();
    }

    #pragma unroll
    for (int i = 0; i < 4; ++i) {
        const int m = bm + ty * 4 + i;
        if (m >= Mm) continue;
        #pragma unroll
        for (int j = 0; j < 4; ++j) {
            const int nn = bn + tx * 4 + j;
            if (nn >= N) continue;
            float v = acc[i][j];
            if (bias) v += bias[nn];
            if (GELU) v = gelu_exact(v);
            if (RES)  v += res[(size_t)m * N + nn];
            C[(size_t)m * N + nn] = v;
        }
    }
}

// ---------------------------------------------------------------------------
// Attention scores: att[bh,q,k] = 0.125 * dot(Q[q], K[k]) + (k<=q ? 1 : 0)
// Q/K live inside qkv [B,T,3D]; head hh occupies cols hh*DH (+D for K).
// NOTE: mask is ADDED (+1 on allowed), softmax runs over all T keys.
// ---------------------------------------------------------------------------
__global__ __launch_bounds__(256) void attn_scores_kernel(
    const float* __restrict__ qkv, float* __restrict__ att)
{
    const int bh = blockIdx.z;
    const int b = bh / H, hh = bh % H;
    const int bq = blockIdx.y * 64;
    const int bk = blockIdx.x * 64;
    const float* Q  = qkv + (size_t)b * T * 3 * D + hh * DH;
    const float* Kp = Q + D;

    __shared__ float Qs[16][65];
    __shared__ float Ks[16][65];
    const int tid = threadIdx.x;
    const int tx = tid & 15, ty = tid >> 4;
    const int r  = tid >> 2;          // 0..63
    const int d4 = (tid & 3) << 2;    // 0,4,8,12

    float acc[4][4] = {};

    for (int k0 = 0; k0 < DH; k0 += 16) {
        {
            float4 v = *reinterpret_cast<const float4*>(&Q[(size_t)(bq + r) * 3 * D + k0 + d4]);
            Qs[d4 + 0][r] = v.x; Qs[d4 + 1][r] = v.y;
            Qs[d4 + 2][r] = v.z; Qs[d4 + 3][r] = v.w;
        }
        {
            float4 v = *reinterpret_cast<const float4*>(&Kp[(size_t)(bk + r) * 3 * D + k0 + d4]);
            Ks[d4 + 0][r] = v.x; Ks[d4 + 1][r] = v.y;
            Ks[d4 + 2][r] = v.z; Ks[d4 + 3][r] = v.w;
        }
        __syncthreads();
        #pragma unroll
        for (int kk = 0; kk < 16; ++kk) {
            float a[4], b2[4];
            #pragma unroll
            for (int i = 0; i < 4; ++i) a[i]  = Qs[kk][ty * 4 + i];
            #pragma unroll
            for (int j = 0; j < 4; ++j) b2[j] = Ks[kk][tx * 4 + j];
            #pragma unroll
            for (int i = 0; i < 4; ++i)
                #pragma unroll
                for (int j = 0; j < 4; ++j)
                    acc[i][j] = fmaf(a[i], b2[j], acc[i][j]);
        }
        __syncthreads();
    }

    #pragma unroll
    for (int i = 0; i < 4; ++i) {
        const int q = bq + ty * 4 + i;
        #pragma unroll
        for (int j = 0; j < 4; ++j) {
            const int k = bk + tx * 4 + j;
            att[((size_t)bh * T + q) * T + k] =
                acc[i][j] * 0.125f + (k <= q ? 1.0f : 0.0f);
        }
    }
}

// ---------------------------------------------------------------------------
// Softmax over rows of length T=512. One wave per row.
// ---------------------------------------------------------------------------
__global__ __launch_bounds__(64) void softmax_kernel(float* __restrict__ att)
{
    float* row = att + (size_t)blockIdx.x * T;
    const int lane = threadIdx.x;
    float v[8];
    float mx = -1e30f;
    #pragma unroll
    for (int i = 0; i < 8; ++i) { v[i] = row[lane + i * 64]; mx = fmaxf(mx, v[i]); }
    #pragma unroll
    for (int off = 32; off; off >>= 1) mx = fmaxf(mx, __shfl_xor(mx, off));
    float s = 0.f;
    #pragma unroll
    for (int i = 0; i < 8; ++i) { v[i] = __expf(v[i] - mx); s += v[i]; }
    #pragma unroll
    for (int off = 32; off; off >>= 1) s += __shfl_xor(s, off);
    const float inv = 1.0f / s;
    #pragma unroll
    for (int i = 0; i < 8; ++i) row[lane + i * 64] = v[i] * inv;
}

// ---------------------------------------------------------------------------
// PV: o[b,q,hh*DH+d] = sum_k att[bh,q,k] * V[b,k,hh*DH+d]  (heads merged out)
// ---------------------------------------------------------------------------
__global__ __launch_bounds__(256) void attn_pv_kernel(
    const float* __restrict__ att, const float* __restrict__ qkv,
    float* __restrict__ o)
{
    const int bh = blockIdx.z;
    const int b = bh / H, hh = bh % H;
    const int bq = blockIdx.y * 64;
    const float* Vp = qkv + (size_t)b * T * 3 * D + 2 * D + hh * DH;
    const float* Am = att + (size_t)bh * T * T;

    __shared__ float As[16][65];
    __shared__ float Vs[16][65];
    const int tid = threadIdx.x;
    const int tx = tid & 15, ty = tid >> 4;
    const int r  = tid >> 2;
    const int k4 = (tid & 3) << 2;

    float acc[4][4] = {};

    for (int k0 = 0; k0 < T; k0 += 16) {
        {
            float4 v = *reinterpret_cast<const float4*>(&Am[(size_t)(bq + r) * T + k0 + k4]);
            As[k4 + 0][r] = v.x; As[k4 + 1][r] = v.y;
            As[k4 + 2][r] = v.z; As[k4 + 3][r] = v.w;
        }
        {
            const int kk = tid >> 4;          // 0..15
            const int dd = (tid & 15) << 2;   // 0..60
            float4 v = *reinterpret_cast<const float4*>(&Vp[(size_t)(k0 + kk) * 3 * D + dd]);
            Vs[kk][dd + 0] = v.x; Vs[kk][dd + 1] = v.y;
            Vs[kk][dd + 2] = v.z; Vs[kk][dd + 3] = v.w;
        }
        __syncthreads();
        #pragma unroll
        for (int kk = 0; kk < 16; ++kk) {
            float a[4], b2[4];
            #pragma unroll
            for (int i = 0; i < 4; ++i) a[i]  = As[kk][ty * 4 + i];
            #pragma unroll
            for (int j = 0; j < 4; ++j) b2[j] = Vs[kk][tx * 4 + j];
            #pragma unroll
            for (int i = 0; i < 4; ++i)
                #pragma unroll
                for (int j = 0; j < 4; ++j)
                    acc[i][j] = fmaf(a[i], b2[j], acc[i][j]);
        }
        __syncthreads();
    }

    #pragma unroll
    for (int i = 0; i < 4; ++i) {
        const int q = bq + ty * 4 + i;
        #pragma unroll
        for (int j = 0; j < 4; ++j) {
            const int d = tx * 4 + j;
            o[((size_t)b * T + q) * D + hh * DH + d] = acc[i][j];
        }
    }
}

// ---------------------------------------------------------------------------
// Launch
// ---------------------------------------------------------------------------
extern "C" void kernel_launch(void* const* d_in, const int* in_sizes, int n_in,
                              void* d_out, int out_size, void* d_ws, size_t ws_size,
                              hipStream_t stream)
{
    const int*   x      = (const int*)  d_in[0];
    const float* vis    = (const float*)d_in[1];
    const float* wte    = (const float*)d_in[2];
    const float* wpe    = (const float*)d_in[3];
    const float* ln1_w  = (const float*)d_in[4];
    const float* ln1_b  = (const float*)d_in[5];
    const float* attn_w = (const float*)d_in[6];
    const float* attn_b = (const float*)d_in[7];
    const float* proj_w = (const float*)d_in[8];
    const float* proj_b = (const float*)d_in[9];
    const float* ln2_w  = (const float*)d_in[10];
    const float* ln2_b  = (const float*)d_in[11];
    const float* fc_w   = (const float*)d_in[12];
    const float* fc_b   = (const float*)d_in[13];
    const float* fc2_w  = (const float*)d_in[14];
    const float* fc2_b  = (const float*)d_in[15];
    const float* lnf_w  = (const float*)d_in[16];
    const float* lnf_b  = (const float*)d_in[17];

    float* out = (float*)d_out;

    // h and n must survive the final head GEMM -> live in d_ws (12.6 MB).
    float* h = (float*)d_ws;
    float* n = h + (size_t)M * D;

    // Dead-by-the-end scratch carved from d_out (out only written at the end):
    // qkv 4.72M + att 12.58M + o 1.57M + mid 6.29M = 25.2M floats << 102.9M.
    float* qkv = out;
    float* att = qkv + (size_t)M * 3 * D;
    float* o   = att + (size_t)B * H * T * T;
    float* mid = o   + (size_t)M * D;

    embed_kernel<<<M, 256, 0, stream>>>(x, vis, wte, wpe, h);

    for (int l = 0; l < L; ++l) {
        ln_kernel<<<M, 256, 0, stream>>>(h, ln1_w + (size_t)l * D, ln1_b + (size_t)l * D, n);

        gemm64<false, false, false><<<dim3(3 * D / 64, M / 64), 256, 0, stream>>>(
            n, attn_w + (size_t)l * D * 3 * D, attn_b + (size_t)l * 3 * D,
            nullptr, qkv, M, 3 * D, D);

        attn_scores_kernel<<<dim3(T / 64, T / 64, B * H), 256, 0, stream>>>(qkv, att);
        softmax_kernel<<<B * H * T, 64, 0, stream>>>(att);
        attn_pv_kernel<<<dim3(1, T / 64, B * H), 256, 0, stream>>>(att, qkv, o);

        gemm64<false, false, true><<<dim3(D / 64, M / 64), 256, 0, stream>>>(
            o, proj_w + (size_t)l * D * D, proj_b + (size_t)l * D,
            h, h, M, D, D);

        ln_kernel<<<M, 256, 0, stream>>>(h, ln2_w + (size_t)l * D, ln2_b + (size_t)l * D, n);

        gemm64<false, true, false><<<dim3(4 * D / 64, M / 64), 256, 0, stream>>>(
            n, fc_w + (size_t)l * D * 4 * D, fc_b + (size_t)l * 4 * D,
            nullptr, mid, M, 4 * D, D);

        gemm64<false, false, true><<<dim3(D / 64, M / 64), 256, 0, stream>>>(
            mid, fc2_w + (size_t)l * 4 * D * D, fc2_b + (size_t)l * D,
            h, h, M, D, 4 * D);
    }

    ln_kernel<<<M, 256, 0, stream>>>(h, lnf_w, lnf_b, n);

    gemm64<true, false, false><<<dim3((V + 63) / 64, M / 64), 256, 0, stream>>>(
        n, wte, nullptr, nullptr, out, M, V, D);
}